// Round 1
// baseline (388.092 us; speedup 1.0000x reference)
//
#include <hip/hip_runtime.h>

#define NFEAT 2048
#define BATCH 16384
#define WPB   4   // waves per block; one row per wave

// One ROW per WAVE. No __syncthreads anywhere:
//  - x row is staged into this wave's private LDS slice via global_load_lds
//    (async, no VGPR round-trip; dest = uniform base + lane*16).
//  - mask/perm are loaded as coalesced int4, issued back-to-back with the
//    stage ops -> ~24 outstanding VMEM ops per wave (one latency exposure).
//  - same-wave LDS visibility needs only s_waitcnt vmcnt(0), not a barrier.
__global__ __launch_bounds__(256) void swap_corrupt_kernel(
    const float* __restrict__ x,
    const int*   __restrict__ mask,
    const int*   __restrict__ perm,
    float*       __restrict__ out)
{
    __shared__ float rows[WPB][NFEAT];   // 32 KB -> 5 blocks/CU (LDS-capped)

    const int t    = threadIdx.x;
    const int w    = t >> 6;
    const int lane = t & 63;
    const int r    = blockIdx.x * WPB + w;
    const size_t base = (size_t)r * NFEAT;

    // ---- stage row r into this wave's LDS slice: 8 x global_load_lds(16B) ----
    // dest semantics: wave-uniform LDS base + lane*16; global source is per-lane.
    auto* lrow = (__attribute__((address_space(3))) float*)(&rows[w][0]);
    const auto* gx = (const __attribute__((address_space(1))) float*)(x + base);
#pragma unroll
    for (int c = 0; c < 8; ++c) {
        __builtin_amdgcn_global_load_lds(
            (const __attribute__((address_space(1))) void*)(gx + c * 256 + lane * 4),
            (__attribute__((address_space(3))) void*)(lrow + c * 256),
            16, 0, 0);
    }

    // ---- issue ALL mask/perm loads (coalesced int4, 16 instrs) ----
    const int4* __restrict__ m4 = (const int4*)(mask + base);
    const int4* __restrict__ p4 = (const int4*)(perm + base);
    int4 m[8], p[8];
#pragma unroll
    for (int c = 0; c < 8; ++c) {
        m[c] = m4[c * 64 + lane];
        p[c] = p4[c * 64 + lane];
    }

    // Staging complete for THIS wave; no cross-wave sharing -> no barrier.
    // (Explicit wait also guards the global_load_lds -> ds_read dependency.)
    asm volatile("s_waitcnt vmcnt(0)" ::: "memory");

    const float* row = &rows[w][0];
    float4* __restrict__ o4 = (float4*)(out + base);
#pragma unroll
    for (int c = 0; c < 8; ++c) {
        const int e0 = c * 256 + lane * 4;
        float4 o;
        o.x = row[m[c].x ? p[c].x : e0    ];
        o.y = row[m[c].y ? p[c].y : e0 + 1];
        o.z = row[m[c].z ? p[c].z : e0 + 2];
        o.w = row[m[c].w ? p[c].w : e0 + 3];
        o4[c * 64 + lane] = o;
    }
}

extern "C" void kernel_launch(void* const* d_in, const int* in_sizes, int n_in,
                              void* d_out, int out_size, void* d_ws, size_t ws_size,
                              hipStream_t stream) {
    const float* x    = (const float*)d_in[0];
    const int*   mask = (const int*)d_in[1];
    const int*   perm = (const int*)d_in[2];
    float*       out  = (float*)d_out;

    swap_corrupt_kernel<<<dim3(BATCH / WPB), dim3(256), 0, stream>>>(x, mask, perm, out);
}